// Round 2
// baseline (881.328 us; speedup 1.0000x reference)
//
#include <hip/hip_runtime.h>
#include <stdint.h>

#define B_ 4
#define HC 256
#define WC 256
#define C_ 128
#define HF 512
#define WF 512
#define NPTS 8192
#define HIDDEN_ 256
#define NPIX (HC*WC)
#define FS 132          // per-pixel feature stride in LDS (129 used, padded for float4)
#define SELW (NPIX/32)  // bitmap words per batch = 2048

// ---------------- K1: copy coarse -> out, clear selection bitmap ----------------
__global__ void pr_copy_clear_kernel(const float4* __restrict__ src, float4* __restrict__ dst,
                                     unsigned* __restrict__ selmap) {
    int i = blockIdx.x * blockDim.x + threadIdx.x;      // 65536 threads
    if (i < B_ * NPIX / 4) dst[i] = src[i];
    if (i < B_ * SELW) selmap[i] = 0u;
}

// ---------------- K2: per-batch radix select of NPTS smallest |coarse| -> bitmap ----------------
__global__ __launch_bounds__(1024) void pr_select_kernel(const float* __restrict__ coarse,
                                                         unsigned* __restrict__ selmap) {
    int b = blockIdx.x;
    const float* cb = coarse + (size_t)b * NPIX;
    int tid = threadIdx.x;
    int lane = tid & 63, wid = tid >> 6;

    __shared__ unsigned hist[256];
    __shared__ unsigned s_prefix;
    __shared__ int s_remk;
    __shared__ unsigned wsum[16];
    __shared__ unsigned s_chosen, s_cless;
    __shared__ unsigned warp_eq[16];
    __shared__ unsigned s_eqbase;

    if (tid == 0) { s_prefix = 0u; s_remk = NPTS; }

    for (int pass = 0; pass < 4; ++pass) {
        if (tid < 256) hist[tid] = 0u;
        __syncthreads();
        unsigned prefix = s_prefix;
        int remk = s_remk;
        int shift = 24 - 8 * pass;

        if (pass == 0) {
            // keys concentrate in few exponent bins -> wave-aggregated atomics
            for (int i = 4 * tid; i < NPIX; i += 4096) {
                float4 v = *(const float4*)(cb + i);
                unsigned bins[4];
                bins[0] = (__float_as_uint(v.x) & 0x7fffffffu) >> 24;
                bins[1] = (__float_as_uint(v.y) & 0x7fffffffu) >> 24;
                bins[2] = (__float_as_uint(v.z) & 0x7fffffffu) >> 24;
                bins[3] = (__float_as_uint(v.w) & 0x7fffffffu) >> 24;
#pragma unroll
                for (int e = 0; e < 4; ++e) {
                    unsigned bin = bins[e];
                    unsigned long long am = ~0ull;
                    while (am) {
                        int leader = __ffsll((unsigned long long)am) - 1;
                        unsigned lbin = __shfl(bin, leader, 64);
                        unsigned long long match = __ballot(bin == lbin);
                        if (lane == leader) atomicAdd(&hist[lbin], (unsigned)__popcll(match));
                        am &= ~match;
                    }
                }
            }
        } else {
            for (int i = 4 * tid; i < NPIX; i += 4096) {
                float4 v = *(const float4*)(cb + i);
                unsigned k0 = __float_as_uint(v.x) & 0x7fffffffu;
                unsigned k1 = __float_as_uint(v.y) & 0x7fffffffu;
                unsigned k2 = __float_as_uint(v.z) & 0x7fffffffu;
                unsigned k3 = __float_as_uint(v.w) & 0x7fffffffu;
                if ((k0 >> (shift + 8)) == prefix) atomicAdd(&hist[(k0 >> shift) & 0xffu], 1u);
                if ((k1 >> (shift + 8)) == prefix) atomicAdd(&hist[(k1 >> shift) & 0xffu], 1u);
                if ((k2 >> (shift + 8)) == prefix) atomicAdd(&hist[(k2 >> shift) & 0xffu], 1u);
                if ((k3 >> (shift + 8)) == prefix) atomicAdd(&hist[(k3 >> shift) & 0xffu], 1u);
            }
        }
        __syncthreads();

        // choose bin: inclusive scan over 256 bins (threads 0..255)
        unsigned h = 0, incl = 0;
        if (tid < 256) {
            h = hist[tid];
            incl = h;
#pragma unroll
            for (int d = 1; d < 64; d <<= 1) {
                unsigned y = __shfl_up(incl, d, 64);
                if (lane >= d) incl += y;
            }
            if (lane == 63) wsum[wid] = incl;
        }
        __syncthreads();
        if (tid < 256) {
            unsigned base = 0;
            for (int w = 0; w < wid; ++w) base += wsum[w];
            unsigned inc = base + incl;
            unsigned exc = inc - h;
            if ((unsigned)remk > exc && (unsigned)remk <= inc) { s_chosen = (unsigned)tid; s_cless = exc; }
        }
        __syncthreads();
        if (tid == 0) { s_prefix = (s_prefix << 8) | s_chosen; s_remk = remk - (int)s_cless; }
        __syncthreads();
    }

    unsigned T = s_prefix;                 // key value of the NPTS-th smallest
    unsigned need_eq = (unsigned)s_remk;   // # of ==T ties to take, smallest index first
    if (tid == 0) s_eqbase = 0u;
    __syncthreads();

    unsigned long long ltmask = (1ull << lane) - 1ull;
    for (int base = 0; base < NPIX; base += 4096) {
        int i0 = base + 4 * tid;
        float4 v = *(const float4*)(cb + i0);
        unsigned k[4];
        k[0] = __float_as_uint(v.x) & 0x7fffffffu;
        k[1] = __float_as_uint(v.y) & 0x7fffffffu;
        k[2] = __float_as_uint(v.z) & 0x7fffffffu;
        k[3] = __float_as_uint(v.w) & 0x7fffffffu;
        bool lt[4], eq[4];
        unsigned long long me[4];
        unsigned weq = 0;
#pragma unroll
        for (int e = 0; e < 4; ++e) {
            lt[e] = k[e] < T;
            eq[e] = k[e] == T;
            me[e] = __ballot(eq[e]);
            weq += (unsigned)__popcll(me[e]);
        }
        if (lane == 0) warp_eq[wid] = weq;
        __syncthreads();

        unsigned eqwb = 0, eqtot = 0;
        for (int w = 0; w < 16; ++w) { unsigned hh = warp_eq[w]; if (w < wid) eqwb += hh; eqtot += hh; }
        unsigned lt_lanes_eq = 0;
#pragma unroll
        for (int e = 0; e < 4; ++e) lt_lanes_eq += (unsigned)__popcll(me[e] & ltmask);
        unsigned ebase = s_eqbase + eqwb + lt_lanes_eq;

        unsigned self_eq = 0;
#pragma unroll
        for (int e = 0; e < 4; ++e) {
            unsigned eqrank = ebase + self_eq;
            bool take = lt[e] || (eq[e] && eqrank < need_eq);
            self_eq += eq[e] ? 1u : 0u;
            if (take) {
                int pix = i0 + e;
                atomicOr(&selmap[b * SELW + (pix >> 5)], 1u << (pix & 31));
            }
        }
        __syncthreads();
        if (tid == 0) s_eqbase += eqtot;
        // next read of s_eqbase is after the next iteration's first __syncthreads
    }
}

// ---------------- K3: fused 2x2 avg-pool (streaming) + in-LDS MLP + scatter ----------------
// Block = one (b, iy, 64-wide ix tile). Pools 64 pixels x 128 ch into LDS,
// then runs the MLP only for this tile's selected pixels. No pooled global buffer.
__global__ __launch_bounds__(512, 4) void pr_pool_mlp_kernel(
    const float* __restrict__ coarse, const float* __restrict__ fine,
    const float* __restrict__ W1, const float* __restrict__ b1,
    const float* __restrict__ W2, const float* __restrict__ b2,
    const unsigned* __restrict__ selmap, float* __restrict__ out) {

    __shared__ __align__(16) float plds[64 * FS];
    __shared__ unsigned char slist[64];
    __shared__ int s_nsel;
    __shared__ float red[2][8][4];

    int tid = threadIdx.x;
    int lane = tid & 63, w = tid >> 6;        // 8 waves
    int pid = blockIdx.x;
    int b   = pid >> 10;                      // 1024 tiles per batch
    int rem = pid & 1023;
    int iy  = rem >> 2;
    int ix0 = (rem & 3) << 6;

    // ---- pool phase: wave handles one channel per iter; lanes 0..31 row 2iy, 32..63 row 2iy+1 ----
    const float* fb = fine + (size_t)b * (C_ * HF * WF);
    int r  = lane >> 5;
    int f4 = lane & 31;
    const float* rowbase = fb + (size_t)(2 * iy + r) * WF + 2 * ix0 + 4 * f4;
#pragma unroll
    for (int half = 0; half < 2; ++half) {
        float4 vv[8];
#pragma unroll
        for (int ci = 0; ci < 8; ++ci) {
            int c = half * 64 + ci * 8 + w;
            vv[ci] = *(const float4*)(rowbase + (size_t)c * (HF * WF));
        }
#pragma unroll
        for (int ci = 0; ci < 8; ++ci) {
            int c = half * 64 + ci * 8 + w;
            float s0 = vv[ci].x + vv[ci].y;       // coarse ix = 2*f4
            float s1 = vv[ci].z + vv[ci].w;       // coarse ix = 2*f4+1
            float p0 = __shfl_xor(s0, 32, 64);    // combine the two fine rows
            float p1 = __shfl_xor(s1, 32, 64);
            if (r == 0) {
                plds[(2 * f4) * FS + c]     = 0.25f * (s0 + p0);
                plds[(2 * f4 + 1) * FS + c] = 0.25f * (s1 + p1);
            }
        }
    }
    if (tid < 64) {
        int pix = iy * WC + ix0 + tid;
        plds[tid * FS + 128] = coarse[(size_t)b * NPIX + pix];
    }
    if (tid == 0) {
        int wbase = b * SELW + ((iy * WC + ix0) >> 5);
        unsigned long long m = ((unsigned long long)selmap[wbase + 1] << 32) | selmap[wbase];
        int n = 0;
        while (m) { int bit = __ffsll(m) - 1; slist[n++] = (unsigned char)bit; m &= m - 1; }
        s_nsel = n;
    }
    __syncthreads();

    // ---- MLP phase: 2 groups x 256 threads; thread j computes hid[j]; 16 points per chunk ----
    int nsel = s_nsel;
    int g = tid >> 8;                 // 0..1
    int j = tid & 255;
    int jl = tid & 63, jw = (tid >> 6) & 3;
    float b1j = b1[j];
    float w2j = W2[j];

    for (int base = 0; base < nsel; base += 16) {
        float acc[8];
        int cix[8];
#pragma unroll
        for (int k = 0; k < 8; ++k) {
            int p = base + 2 * k + g;
            cix[k] = (p < nsel) ? (int)slist[p] : 0;
            acc[k] = b1j;
        }
#pragma unroll 4
        for (int f4i = 0; f4i < 32; ++f4i) {
            float w0 = W1[(4 * f4i + 0) * HIDDEN_ + j];
            float w1 = W1[(4 * f4i + 1) * HIDDEN_ + j];
            float w2 = W1[(4 * f4i + 2) * HIDDEN_ + j];
            float w3 = W1[(4 * f4i + 3) * HIDDEN_ + j];
#pragma unroll
            for (int k = 0; k < 8; ++k) {
                float4 fv = *(const float4*)&plds[cix[k] * FS + 4 * f4i];
                acc[k] = fmaf(fv.x, w0, acc[k]);
                acc[k] = fmaf(fv.y, w1, acc[k]);
                acc[k] = fmaf(fv.z, w2, acc[k]);
                acc[k] = fmaf(fv.w, w3, acc[k]);
            }
        }
        {
            float w128 = W1[128 * HIDDEN_ + j];
#pragma unroll
            for (int k = 0; k < 8; ++k)
                acc[k] = fmaf(plds[cix[k] * FS + 128], w128, acc[k]);
        }
#pragma unroll
        for (int k = 0; k < 8; ++k) {
            float v = fmaxf(acc[k], 0.0f) * w2j;
            v += __shfl_down(v, 32, 64);
            v += __shfl_down(v, 16, 64);
            v += __shfl_down(v, 8, 64);
            v += __shfl_down(v, 4, 64);
            v += __shfl_down(v, 2, 64);
            v += __shfl_down(v, 1, 64);
            if (jl == 0) red[g][k][jw] = v;
        }
        __syncthreads();
        if (tid < 16) {
            int g2 = tid & 1, k2 = tid >> 1;
            int p = base + 2 * k2 + g2;
            if (p < nsel) {
                float rr = red[g2][k2][0] + red[g2][k2][1] + red[g2][k2][2] + red[g2][k2][3] + b2[0];
                out[(size_t)b * NPIX + iy * WC + ix0 + (int)slist[p]] = rr;
            }
        }
        __syncthreads();   // protect red[] reuse in next chunk
    }
}

extern "C" void kernel_launch(void* const* d_in, const int* in_sizes, int n_in,
                              void* d_out, int out_size, void* d_ws, size_t ws_size,
                              hipStream_t stream) {
    const float* coarse = (const float*)d_in[0];
    const float* fine   = (const float*)d_in[1];
    const float* W1     = (const float*)d_in[2];
    const float* b1     = (const float*)d_in[3];
    const float* W2     = (const float*)d_in[4];
    const float* b2     = (const float*)d_in[5];
    float* out = (float*)d_out;
    unsigned* selmap = (unsigned*)d_ws;    // B_ * 2048 words = 32 KB

    pr_copy_clear_kernel<<<256, 256, 0, stream>>>((const float4*)coarse, (float4*)out, selmap);
    pr_select_kernel<<<B_, 1024, 0, stream>>>(coarse, selmap);
    pr_pool_mlp_kernel<<<B_ * HC * 4, 512, 0, stream>>>(coarse, fine, W1, b1, W2, b2, selmap, out);
}

// Round 3
// 777.010 us; speedup vs baseline: 1.1343x; 1.1343x over previous
//
#include <hip/hip_runtime.h>
#include <stdint.h>

#define B_ 4
#define HC 256
#define WC 256
#define C_ 128
#define HF 512
#define WF 512
#define NPTS 8192
#define HIDDEN_ 256
#define NPIX (HC*WC)
#define PPB 16
#define FSTRIDE 132
#define PSTRIDE 129   // LDS transpose tile stride (64 x 129 floats)
#define NCOPY 16      // copy blocks fused into the select/pool kernel

// ---------------- fused: select (blocks 0..3) + copy (blocks 4..19) + avg-pool transpose ----
// pooled layout: [B][HC][WC][C] so the MLP gather reads 128 contiguous floats per point.
__global__ __launch_bounds__(1024) void pr_select_pool_kernel(
        const float* __restrict__ coarse, const float* __restrict__ fine,
        int* __restrict__ sel, float* __restrict__ pooled,
        const float4* __restrict__ src4, float4* __restrict__ dst4) {
    int tid = threadIdx.x;
    int lane = tid & 63, wid = tid >> 6;

    if (blockIdx.x >= B_ && blockIdx.x < B_ + NCOPY) {
        // ---------- copy coarse -> out (16 blocks x 1024 thr x 4 float4) ----------
        int cb = blockIdx.x - B_;
#pragma unroll
        for (int k = 0; k < 4; ++k) {
            int i = cb * 4096 + k * 1024 + tid;   // 16*4096 = 65536 float4 = 1 MB
            dst4[i] = src4[i];
        }
        return;
    }

    if (blockIdx.x >= B_ + NCOPY) {
        // ---------- avg-pool 2x2 + transpose to [iy][ix][c] ----------
        __shared__ float plds[64 * PSTRIDE];      // 64 coarse ix x 128 ch (padded)
        int pid = blockIdx.x - B_ - NCOPY;        // 0 .. B_*HC*4 - 1
        int b   = pid >> 10;                      // HC*4 = 1024 blocks per batch
        int rem = pid & 1023;
        int iy  = rem >> 2;
        int ix0 = (rem & 3) << 6;                 // 64 coarse ix per block
        const float* fb = fine + (size_t)b * (C_ * HF * WF);
        int r  = lane >> 5;                       // row within 2x2 (0/1)
        int f4 = lane & 31;                       // float4 index along fine x
        const float* rowbase = fb + (size_t)(2 * iy + r) * WF + 2 * ix0 + 4 * f4;
        // 16 waves x 8 iterations = 128 channels; each wave-iter reads two
        // coalesced 512B row segments of one channel.
#pragma unroll
        for (int ci = 0; ci < 8; ++ci) {
            int c = ci * 16 + wid;
            float4 v = *(const float4*)(rowbase + (size_t)c * (HF * WF));
            float s0 = v.x + v.y;                 // coarse ix = 2*f4
            float s1 = v.z + v.w;                 // coarse ix = 2*f4+1
            float p0 = __shfl_xor(s0, 32, 64);    // combine rows 2iy / 2iy+1
            float p1 = __shfl_xor(s1, 32, 64);
            if (r == 0) {
                int cix = 2 * f4;
                plds[cix * PSTRIDE + c]       = 0.25f * (s0 + p0);
                plds[(cix + 1) * PSTRIDE + c] = 0.25f * (s1 + p1);
            }
        }
        __syncthreads();
        float* ob = pooled + ((size_t)b * NPIX + iy * WC + ix0) * C_;
#pragma unroll
        for (int k = 0; k < 2; ++k) {
            int g  = tid + k * 1024;              // 2048 float4 per tile
            int ix = g >> 5;
            int c4 = (g & 31) * 4;
            float4 o;
            o.x = plds[ix * PSTRIDE + c4 + 0];
            o.y = plds[ix * PSTRIDE + c4 + 1];
            o.z = plds[ix * PSTRIDE + c4 + 2];
            o.w = plds[ix * PSTRIDE + c4 + 3];
            *(float4*)(ob + (size_t)ix * C_ + c4) = o;   // fully coalesced
        }
        return;
    }

    // ---------- per-batch radix select of NPTS smallest |coarse|, ordered output ----------
    int b = blockIdx.x;
    const float* cb = coarse + (size_t)b * NPIX;

    __shared__ unsigned hist[256];
    __shared__ unsigned s_prefix;
    __shared__ int s_remk;
    __shared__ unsigned wsum[16];
    __shared__ unsigned s_chosen, s_cless;
    __shared__ unsigned warp_eq[16], warp_take[16];
    __shared__ unsigned s_eqbase, s_outbase;

    if (tid == 0) { s_prefix = 0u; s_remk = NPTS; }

    for (int pass = 0; pass < 4; ++pass) {
        if (tid < 256) hist[tid] = 0u;
        __syncthreads();
        unsigned prefix = s_prefix;
        int remk = s_remk;
        int shift = 24 - 8 * pass;

        if (pass == 0) {
            // keys concentrate in ~10 exponent bins -> wave-aggregated atomics
            for (int i = 4 * tid; i < NPIX; i += 4096) {
                float4 v = *(const float4*)(cb + i);
                unsigned bins[4];
                bins[0] = (__float_as_uint(v.x) & 0x7fffffffu) >> 24;
                bins[1] = (__float_as_uint(v.y) & 0x7fffffffu) >> 24;
                bins[2] = (__float_as_uint(v.z) & 0x7fffffffu) >> 24;
                bins[3] = (__float_as_uint(v.w) & 0x7fffffffu) >> 24;
#pragma unroll
                for (int e = 0; e < 4; ++e) {
                    unsigned bin = bins[e];
                    unsigned long long am = ~0ull;
                    while (am) {
                        int leader = __ffsll((unsigned long long)am) - 1;
                        unsigned lbin = __shfl(bin, leader, 64);
                        unsigned long long match = __ballot(bin == lbin);
                        if (lane == leader) atomicAdd(&hist[lbin], (unsigned)__popcll(match));
                        am &= ~match;
                    }
                }
            }
        } else {
            for (int i = 4 * tid; i < NPIX; i += 4096) {
                float4 v = *(const float4*)(cb + i);
                unsigned k0 = __float_as_uint(v.x) & 0x7fffffffu;
                unsigned k1 = __float_as_uint(v.y) & 0x7fffffffu;
                unsigned k2 = __float_as_uint(v.z) & 0x7fffffffu;
                unsigned k3 = __float_as_uint(v.w) & 0x7fffffffu;
                if ((k0 >> (shift + 8)) == prefix) atomicAdd(&hist[(k0 >> shift) & 0xffu], 1u);
                if ((k1 >> (shift + 8)) == prefix) atomicAdd(&hist[(k1 >> shift) & 0xffu], 1u);
                if ((k2 >> (shift + 8)) == prefix) atomicAdd(&hist[(k2 >> shift) & 0xffu], 1u);
                if ((k3 >> (shift + 8)) == prefix) atomicAdd(&hist[(k3 >> shift) & 0xffu], 1u);
            }
        }
        __syncthreads();

        unsigned h = 0, incl = 0;
        if (tid < 256) {
            h = hist[tid];
            incl = h;
#pragma unroll
            for (int d = 1; d < 64; d <<= 1) {
                unsigned y = __shfl_up(incl, d, 64);
                if (lane >= d) incl += y;
            }
            if (lane == 63) wsum[wid] = incl;
        }
        __syncthreads();
        if (tid < 256) {
            unsigned base = 0;
            for (int w = 0; w < wid; ++w) base += wsum[w];
            unsigned inc = base + incl;
            unsigned exc = inc - h;
            if ((unsigned)remk > exc && (unsigned)remk <= inc) { s_chosen = (unsigned)tid; s_cless = exc; }
        }
        __syncthreads();
        if (tid == 0) { s_prefix = (s_prefix << 8) | s_chosen; s_remk = remk - (int)s_cless; }
        __syncthreads();
    }

    unsigned T = s_prefix;
    unsigned need_eq = (unsigned)s_remk;
    if (tid == 0) { s_eqbase = 0u; s_outbase = 0u; }
    __syncthreads();

    unsigned long long ltmask = (1ull << lane) - 1ull;
    for (int base = 0; base < NPIX; base += 4096) {
        int i0 = base + 4 * tid;
        float4 v = *(const float4*)(cb + i0);
        unsigned k[4];
        k[0] = __float_as_uint(v.x) & 0x7fffffffu;
        k[1] = __float_as_uint(v.y) & 0x7fffffffu;
        k[2] = __float_as_uint(v.z) & 0x7fffffffu;
        k[3] = __float_as_uint(v.w) & 0x7fffffffu;
        bool lt[4], eq[4];
        unsigned long long me[4];
        unsigned weq = 0;
#pragma unroll
        for (int e = 0; e < 4; ++e) {
            lt[e] = k[e] < T;
            eq[e] = k[e] == T;
            me[e] = __ballot(eq[e]);
            weq += (unsigned)__popcll(me[e]);
        }
        if (lane == 0) warp_eq[wid] = weq;
        __syncthreads();

        unsigned eqwb = 0, eqtot = 0;
        for (int w = 0; w < 16; ++w) { unsigned hh = warp_eq[w]; if (w < wid) eqwb += hh; eqtot += hh; }
        unsigned lt_lanes_eq = 0;
#pragma unroll
        for (int e = 0; e < 4; ++e) lt_lanes_eq += (unsigned)__popcll(me[e] & ltmask);
        unsigned ebase = s_eqbase + eqwb + lt_lanes_eq;

        bool take[4];
        unsigned long long mt[4];
        unsigned self_eq = 0;
#pragma unroll
        for (int e = 0; e < 4; ++e) {
            unsigned eqrank = ebase + self_eq;
            take[e] = lt[e] || (eq[e] && eqrank < need_eq);
            self_eq += eq[e] ? 1u : 0u;
        }
        unsigned wtk = 0;
#pragma unroll
        for (int e = 0; e < 4; ++e) {
            mt[e] = __ballot(take[e]);
            wtk += (unsigned)__popcll(mt[e]);
        }
        if (lane == 0) warp_take[wid] = wtk;
        __syncthreads();

        unsigned twb = 0, ttot = 0;
        for (int w = 0; w < 16; ++w) { unsigned hh = warp_take[w]; if (w < wid) twb += hh; ttot += hh; }
        unsigned lt_lanes_tk = 0;
#pragma unroll
        for (int e = 0; e < 4; ++e) lt_lanes_tk += (unsigned)__popcll(mt[e] & ltmask);
        unsigned tbase = s_outbase + twb + lt_lanes_tk;
        unsigned self_tk = 0;
#pragma unroll
        for (int e = 0; e < 4; ++e) {
            if (take[e]) sel[b * NPTS + (int)(tbase + self_tk)] = i0 + e;
            self_tk += take[e] ? 1u : 0u;
        }
        __syncthreads();
        if (tid == 0) { s_eqbase += eqtot; s_outbase += ttot; }
    }
}

// ---------------- gather (from pooled, coalesced) + MLP + scatter ----------------
__global__ __launch_bounds__(256) void pr_mlp_pooled_kernel(
    const float* __restrict__ coarse, const float* __restrict__ pooled,
    const float* __restrict__ W1, const float* __restrict__ b1,
    const float* __restrict__ W2, const float* __restrict__ b2,
    const int* __restrict__ sel, float* __restrict__ out) {

    __shared__ __align__(16) float feats[PPB * FSTRIDE];
    __shared__ int sidx[PPB];
    __shared__ float red[PPB][4];

    int tid = threadIdx.x;
    const int bpb = NPTS / PPB;
    int b = blockIdx.x / bpb;
    int pbase = (blockIdx.x % bpb) * PPB;

    if (tid < PPB) sidx[tid] = sel[b * NPTS + pbase + tid];
    __syncthreads();

    {   // 16 threads per point, 8 contiguous floats each: fully coalesced 512B/point
        int p = tid >> 4, q = tid & 15;
        const float* prow = pooled + ((size_t)b * NPIX + sidx[p]) * C_ + 8 * q;
        float4 v0 = *(const float4*)(prow);
        float4 v1 = *(const float4*)(prow + 4);
        *(float4*)&feats[p * FSTRIDE + 8 * q]     = v0;
        *(float4*)&feats[p * FSTRIDE + 8 * q + 4] = v1;
    }
    if (tid < PPB) feats[tid * FSTRIDE + 128] = coarse[(size_t)b * NPIX + sidx[tid]];
    __syncthreads();

    int j = tid;
    float acc[PPB];
    float b1j = b1[j];
#pragma unroll
    for (int p = 0; p < PPB; ++p) acc[p] = b1j;

    const float4* fs4 = (const float4*)feats;
#pragma unroll 4
    for (int f4 = 0; f4 < 32; ++f4) {
        float w0 = W1[(4 * f4 + 0) * HIDDEN_ + j];
        float w1 = W1[(4 * f4 + 1) * HIDDEN_ + j];
        float w2 = W1[(4 * f4 + 2) * HIDDEN_ + j];
        float w3 = W1[(4 * f4 + 3) * HIDDEN_ + j];
#pragma unroll
        for (int p = 0; p < PPB; ++p) {
            float4 fv = fs4[p * (FSTRIDE / 4) + f4];
            acc[p] = fmaf(fv.x, w0, acc[p]);
            acc[p] = fmaf(fv.y, w1, acc[p]);
            acc[p] = fmaf(fv.z, w2, acc[p]);
            acc[p] = fmaf(fv.w, w3, acc[p]);
        }
    }
    {
        float w128 = W1[128 * HIDDEN_ + j];
#pragma unroll
        for (int p = 0; p < PPB; ++p) acc[p] = fmaf(feats[p * FSTRIDE + 128], w128, acc[p]);
    }

    float w2j = W2[j];
    int lane = tid & 63, wid = tid >> 6;
#pragma unroll
    for (int p = 0; p < PPB; ++p) {
        float v = fmaxf(acc[p], 0.0f) * w2j;
        v += __shfl_down(v, 32, 64);
        v += __shfl_down(v, 16, 64);
        v += __shfl_down(v, 8, 64);
        v += __shfl_down(v, 4, 64);
        v += __shfl_down(v, 2, 64);
        v += __shfl_down(v, 1, 64);
        if (lane == 0) red[p][wid] = v;
    }
    __syncthreads();
    if (tid < PPB) {
        float r = red[tid][0] + red[tid][1] + red[tid][2] + red[tid][3] + b2[0];
        out[(size_t)b * NPIX + sidx[tid]] = r;
    }
}

// ---------------- fallback: direct scattered gather ----------------
__global__ __launch_bounds__(256) void pr_mlp_kernel(
    const float* __restrict__ coarse, const float* __restrict__ fine,
    const float* __restrict__ W1, const float* __restrict__ b1,
    const float* __restrict__ W2, const float* __restrict__ b2,
    const int* __restrict__ sel, float* __restrict__ out) {

    __shared__ __align__(16) float feats[PPB * FSTRIDE];
    __shared__ int sidx[PPB];
    __shared__ float red[PPB][4];

    int tid = threadIdx.x;
    const int bpb = NPTS / PPB;
    int b = blockIdx.x / bpb;
    int pbase = (blockIdx.x % bpb) * PPB;

    if (tid < PPB) sidx[tid] = sel[b * NPTS + pbase + tid];
    __syncthreads();

    const float* fb = fine + (size_t)b * (C_ * HF * WF);
    int c = tid & 127;
    int ph = tid >> 7;

    float2 r0[PPB / 2], r1[PPB / 2];
#pragma unroll
    for (int k = 0; k < PPB / 2; ++k) {
        int p = 2 * k + ph;
        int id = sidx[p];
        int ix = id & (WC - 1), iy = id >> 8;
        const float* a = fb + (size_t)c * (HF * WF) + (size_t)(2 * iy) * WF + 2 * ix;
        r0[k] = *(const float2*)a;
        r1[k] = *(const float2*)(a + WF);
    }
#pragma unroll
    for (int k = 0; k < PPB / 2; ++k) {
        int p = 2 * k + ph;
        feats[p * FSTRIDE + c] = 0.25f * ((r0[k].x + r0[k].y) + (r1[k].x + r1[k].y));
    }
    if (tid < PPB) feats[tid * FSTRIDE + 128] = coarse[(size_t)b * NPIX + sidx[tid]];
    __syncthreads();

    int j = tid;
    float acc[PPB];
    float b1j = b1[j];
#pragma unroll
    for (int p = 0; p < PPB; ++p) acc[p] = b1j;

    const float4* fs4 = (const float4*)feats;
#pragma unroll 4
    for (int f4 = 0; f4 < 32; ++f4) {
        float w0 = W1[(4 * f4 + 0) * HIDDEN_ + j];
        float w1 = W1[(4 * f4 + 1) * HIDDEN_ + j];
        float w2 = W1[(4 * f4 + 2) * HIDDEN_ + j];
        float w3 = W1[(4 * f4 + 3) * HIDDEN_ + j];
#pragma unroll
        for (int p = 0; p < PPB; ++p) {
            float4 fv = fs4[p * (FSTRIDE / 4) + f4];
            acc[p] = fmaf(fv.x, w0, acc[p]);
            acc[p] = fmaf(fv.y, w1, acc[p]);
            acc[p] = fmaf(fv.z, w2, acc[p]);
            acc[p] = fmaf(fv.w, w3, acc[p]);
        }
    }
    {
        float w128 = W1[128 * HIDDEN_ + j];
#pragma unroll
        for (int p = 0; p < PPB; ++p) acc[p] = fmaf(feats[p * FSTRIDE + 128], w128, acc[p]);
    }

    float w2j = W2[j];
    int lane = tid & 63, wid = tid >> 6;
#pragma unroll
    for (int p = 0; p < PPB; ++p) {
        float v = fmaxf(acc[p], 0.0f) * w2j;
        v += __shfl_down(v, 32, 64);
        v += __shfl_down(v, 16, 64);
        v += __shfl_down(v, 8, 64);
        v += __shfl_down(v, 4, 64);
        v += __shfl_down(v, 2, 64);
        v += __shfl_down(v, 1, 64);
        if (lane == 0) red[p][wid] = v;
    }
    __syncthreads();
    if (tid < PPB) {
        float r = red[tid][0] + red[tid][1] + red[tid][2] + red[tid][3] + b2[0];
        out[(size_t)b * NPIX + sidx[tid]] = r;
    }
}

extern "C" void kernel_launch(void* const* d_in, const int* in_sizes, int n_in,
                              void* d_out, int out_size, void* d_ws, size_t ws_size,
                              hipStream_t stream) {
    const float* coarse = (const float*)d_in[0];
    const float* fine   = (const float*)d_in[1];
    const float* W1     = (const float*)d_in[2];
    const float* b1     = (const float*)d_in[3];
    const float* W2     = (const float*)d_in[4];
    const float* b2     = (const float*)d_in[5];
    float* out = (float*)d_out;

    int* sel = (int*)d_ws;
    const size_t selBytes    = (size_t)B_ * NPTS * sizeof(int);          // 128 KB
    const size_t pooledBytes = (size_t)B_ * NPIX * C_ * sizeof(float);   // 128 MB

    if (ws_size >= selBytes + pooledBytes) {
        float* pooled = (float*)((char*)d_ws + selBytes);
        // blocks 0..3: radix select; 4..19: coarse->out copy; 20..4115: avg-pool
        // transpose (HBM-bound) -> select & copy hide under the pool.
        pr_select_pool_kernel<<<B_ + NCOPY + B_ * HC * (WC / 64), 1024, 0, stream>>>(
            coarse, fine, sel, pooled, (const float4*)coarse, (float4*)out);
        pr_mlp_pooled_kernel<<<B_ * (NPTS / PPB), 256, 0, stream>>>(coarse, pooled, W1, b1, W2, b2, sel, out);
    } else {
        // fallback: select + copy only, then direct scattered gather
        pr_select_pool_kernel<<<B_ + NCOPY, 1024, 0, stream>>>(
            coarse, fine, sel, (float*)nullptr, (const float4*)coarse, (float4*)out);
        pr_mlp_kernel<<<B_ * (NPTS / PPB), 256, 0, stream>>>(coarse, fine, W1, b1, W2, b2, sel, out);
    }
}